// Round 7
// baseline (1644.037 us; speedup 1.0000x reference)
//
#include <hip/hip_runtime.h>

#define D 256

typedef __attribute__((ext_vector_type(8))) short bf16x8;
typedef __attribute__((ext_vector_type(4))) float f32x4;

__device__ inline unsigned short f2bf(float f) {
  union { float f; unsigned u; } v; v.f = f;
  unsigned r = v.u + 0x7FFFu + ((v.u >> 16) & 1u);
  return (unsigned short)(r >> 16);
}
__device__ inline float bf2f(unsigned short u) {
  union { unsigned u; float f; } v; v.u = ((unsigned)u) << 16;
  return v.f;
}

// Convert fp32 W[b][k][n] (n==D) -> bf16 fragment-major W':
//   W'[((kt*(D/16)+ct)*64 + lane)*8 + j]  where k=kt*32+(lane>>4)*8+j, col=ct*16+(lane&15)
__global__ void wprep_kernel(const float* __restrict__ w, unsigned short* __restrict__ wt,
                             int K, int total) {
  int idx = blockIdx.x * 256 + threadIdx.x;
  if (idx >= total) return;
  int per_b = K * D;
  int b = idx / per_b;
  int r = idx % per_b;
  int j = r & 7;
  int lane = (r >> 3) & 63;
  int t = r >> 9;            // kt*16 + ct
  int kt = t >> 4, ct = t & 15;
  int k = kt * 32 + (lane >> 4) * 8 + j;
  int col = ct * 16 + (lane & 15);
  wt[idx] = f2bf(w[((size_t)b * K + k) * D + col]);
}

__global__ void cvt_bf16_kernel(const float4* __restrict__ in, ushort4* __restrict__ out, int n4) {
  int i = blockIdx.x * 256 + threadIdx.x;
  if (i >= n4) return;
  float4 f = in[i];
  ushort4 o;
  o.x = f2bf(f.x); o.y = f2bf(f.y); o.z = f2bf(f.z); o.w = f2bf(f.w);
  out[i] = o;
}

// ---- CSR build ----
__global__ void hist_kernel(const int* __restrict__ dst, int* __restrict__ hist, int E) {
  int i = blockIdx.x * 256 + threadIdx.x;
  if (i < E) atomicAdd(&hist[dst[i]], 1);
}

__global__ void scan_kernel(const int* __restrict__ hist, int* __restrict__ offs, int Nn) {
  __shared__ int part[256];
  int t = threadIdx.x;
  int chunk = (Nn + 255) >> 8;
  int s = t * chunk;
  int e = s + chunk; if (e > Nn) e = Nn; if (s > Nn) s = Nn;
  int sum = 0;
  for (int i = s; i < e; ++i) sum += hist[i];
  part[t] = sum;
  __syncthreads();
  if (t == 0) {
    int run = 0;
    for (int i = 0; i < 256; ++i) { int v = part[i]; part[i] = run; run += v; }
  }
  __syncthreads();
  int run = part[t];
  for (int i = s; i < e; ++i) { offs[i] = run; run += hist[i]; }
  if (e == Nn) offs[Nn] = run;
}

__global__ void fill_kernel(const int* __restrict__ dst, const int* __restrict__ offs,
                            int* __restrict__ cnt, int* __restrict__ eid, int E) {
  int i = blockIdx.x * 256 + threadIdx.x;
  if (i < E) {
    int d = dst[i];
    int p = offs[d] + atomicAdd(&cnt[d], 1);
    eid[p] = i;
  }
}

// agg[node] = sum over CSR bucket of eabf rows (bf16 in, bf16 out). One wave/node.
__global__ __launch_bounds__(256) void agg_kernel(
    const unsigned short* __restrict__ eabf, const int* __restrict__ eid,
    const int* __restrict__ offs, unsigned short* __restrict__ aggbf, int Nn) {
  int node = blockIdx.x * 4 + (threadIdx.x >> 6);
  if (node >= Nn) return;
  int lane = threadIdx.x & 63;
  int s = offs[node], e = offs[node + 1];
  float4 acc = make_float4(0.f, 0.f, 0.f, 0.f);
  for (int i = s; i < e; ++i) {
    int ed = eid[i];
    ushort4 v = *(const ushort4*)(eabf + (size_t)ed * D + lane * 4);
    acc.x += bf2f(v.x); acc.y += bf2f(v.y); acc.z += bf2f(v.z); acc.w += bf2f(v.w);
  }
  ushort4 o;
  o.x = f2bf(acc.x); o.y = f2bf(acc.y); o.z = f2bf(acc.z); o.w = f2bf(acc.w);
  *(ushort4*)(aggbf + (size_t)node * D + lane * 4) = o;
}

// Fused 3-layer MLP, 32-row M-tile, depth-3 rotating register prefetch.
//   res += LN(relu(relu(A@W1+b1)@W2+b2)@W3+b3)*g+b
// A = concat of NCHUNK bf16 256-wide chunks (chunk0 gather g0, chunk1 gather g1).
// W* fragment-major (see wprep). resid!=null: fp32 RMW + optional bf16 shadow.
// resid==null: bf16 RMW on bfout.
template<int NCHUNK>
__global__ __launch_bounds__(256, 4) void fused_mlp(
    const unsigned short* __restrict__ C0, const int* __restrict__ g0,
    const unsigned short* __restrict__ C1, const int* __restrict__ g1,
    const unsigned short* __restrict__ C2,
    const unsigned short* __restrict__ W1, const float* __restrict__ b1,
    const unsigned short* __restrict__ W2, const float* __restrict__ b2,
    const unsigned short* __restrict__ W3, const float* __restrict__ b3,
    const float* __restrict__ lng, const float* __restrict__ lnb,
    float* __restrict__ resid, unsigned short* __restrict__ bfout, int M)
{
  __shared__ __align__(16) unsigned short Hs[32 * 264];  // 16896 B, h1/h2 (+8 pad)
  __shared__ float ps1[128];
  __shared__ float ps2[128];

  const int tid  = threadIdx.x;
  const int lane = tid & 63;
  const int wave = tid >> 6;
  const int lr   = lane & 15;
  const int lq   = lane >> 4;
  const int r0   = blockIdx.x * 32;

  // per-lane A-row element offsets for the 2 m-tiles, per chunk
  int ro0[2], ro1[2], ro2[2];
  #pragma unroll
  for (int mt = 0; mt < 2; ++mt) {
    int rw = r0 + mt * 16 + lr;
    if (rw > M - 1) rw = M - 1;
    ro0[mt] = (g0 ? g0[rw] : rw) * D;
    ro1[mt] = (NCHUNK > 1) ? ((g1 ? g1[rw] : rw) * D) : 0;
    ro2[mt] = (NCHUNK > 2) ? rw * D : 0;
  }

  f32x4 acc[2][4];

  const int ctb = wave * 4;   // this wave's first col-tile
  #define LOADB(Wp, kt, dst)                                                  \
    _Pragma("unroll")                                                         \
    for (int nt = 0; nt < 4; ++nt)                                            \
      dst[nt] = *(const bf16x8*)((Wp) + ((((kt) * 16 + ctb + nt) * 64 + lane) * 8));

  #define LOADA(kt, dst) {                                                    \
    const int c_ = (kt) >> 3;                                                 \
    const int koff_ = (((kt) & 7) << 5) + lq * 8;                             \
    const unsigned short* bp_ = (c_ == 0) ? C0 : (c_ == 1 ? C1 : C2);         \
    _Pragma("unroll")                                                         \
    for (int mt = 0; mt < 2; ++mt) {                                          \
      int r_ = ro0[mt];                                                       \
      if (NCHUNK > 1 && c_ == 1) r_ = ro1[mt];                                \
      if (NCHUNK > 2 && c_ == 2) r_ = ro2[mt];                                \
      dst[mt] = *(const bf16x8*)(bp_ + r_ + koff_);                           \
    }                                                                         \
  }

  constexpr int DEPTH = 3;
  bf16x8 afb[DEPTH][2], bqb[DEPTH][4];

  // ---------------- Layer 1 (K = NCHUNK*256) ----------------
  #pragma unroll
  for (int i = 0; i < 2; i++)
    #pragma unroll
    for (int j = 0; j < 4; j++)
      acc[i][j] = (f32x4){0.f, 0.f, 0.f, 0.f};

  constexpr int NKT = NCHUNK * 8;
  #pragma unroll
  for (int d = 0; d < DEPTH; ++d) {
    LOADA(d, afb[d]);
    LOADB(W1, d, bqb[d]);
  }
  #pragma unroll
  for (int kt = 0; kt < NKT; ++kt) {
    const int s = kt % DEPTH;
    #pragma unroll
    for (int mt = 0; mt < 2; ++mt)
      #pragma unroll
      for (int nt = 0; nt < 4; ++nt)
        acc[mt][nt] = __builtin_amdgcn_mfma_f32_16x16x32_bf16(afb[s][mt], bqb[s][nt], acc[mt][nt], 0, 0, 0);
    if (kt + DEPTH < NKT) {
      LOADA(kt + DEPTH, afb[s]);
      LOADB(W1, kt + DEPTH, bqb[s]);
    }
  }
  // epilogue: bias + relu -> Hs (each wave owns cols wave*64..+63; no race)
  {
    float bv[4];
    #pragma unroll
    for (int nt = 0; nt < 4; ++nt) bv[nt] = b1[wave * 64 + nt * 16 + lr];
    #pragma unroll
    for (int mt = 0; mt < 2; ++mt)
      #pragma unroll
      for (int r = 0; r < 4; ++r) {
        const int row = mt * 16 + lq * 4 + r;
        #pragma unroll
        for (int nt = 0; nt < 4; ++nt) {
          float v = acc[mt][nt][r] + bv[nt];
          v = v > 0.f ? v : 0.f;
          Hs[row * 264 + wave * 64 + nt * 16 + lr] = f2bf(v);
        }
      }
  }
  __syncthreads();   // h1 visible to all waves

  // ---------------- Layer 2 (K = 256, A from Hs) ----------------
  #pragma unroll
  for (int i = 0; i < 2; i++)
    #pragma unroll
    for (int j = 0; j < 4; j++)
      acc[i][j] = (f32x4){0.f, 0.f, 0.f, 0.f};
  #pragma unroll
  for (int d = 0; d < DEPTH; ++d) LOADB(W2, d, bqb[d]);
  #pragma unroll
  for (int kt = 0; kt < 8; ++kt) {
    const int s = kt % DEPTH;
    bf16x8 afc[2];
    #pragma unroll
    for (int mt = 0; mt < 2; ++mt)
      afc[mt] = *(const bf16x8*)&Hs[(mt * 16 + lr) * 264 + (kt << 5) + lq * 8];
    #pragma unroll
    for (int mt = 0; mt < 2; ++mt)
      #pragma unroll
      for (int nt = 0; nt < 4; ++nt)
        acc[mt][nt] = __builtin_amdgcn_mfma_f32_16x16x32_bf16(afc[mt], bqb[s][nt], acc[mt][nt], 0, 0, 0);
    if (kt + DEPTH < 8) LOADB(W2, kt + DEPTH, bqb[s]);
  }
  __syncthreads();   // all h1 reads done before overwrite
  {
    float bv[4];
    #pragma unroll
    for (int nt = 0; nt < 4; ++nt) bv[nt] = b2[wave * 64 + nt * 16 + lr];
    #pragma unroll
    for (int mt = 0; mt < 2; ++mt)
      #pragma unroll
      for (int r = 0; r < 4; ++r) {
        const int row = mt * 16 + lq * 4 + r;
        #pragma unroll
        for (int nt = 0; nt < 4; ++nt) {
          float v = acc[mt][nt][r] + bv[nt];
          v = v > 0.f ? v : 0.f;
          Hs[row * 264 + wave * 64 + nt * 16 + lr] = f2bf(v);
        }
      }
  }
  __syncthreads();   // h2 visible

  // ---------------- Layer 3 (K = 256) + LayerNorm + residual ----------------
  #pragma unroll
  for (int i = 0; i < 2; i++)
    #pragma unroll
    for (int j = 0; j < 4; j++)
      acc[i][j] = (f32x4){0.f, 0.f, 0.f, 0.f};
  #pragma unroll
  for (int d = 0; d < DEPTH; ++d) LOADB(W3, d, bqb[d]);
  #pragma unroll
  for (int kt = 0; kt < 8; ++kt) {
    const int s = kt % DEPTH;
    bf16x8 afc[2];
    #pragma unroll
    for (int mt = 0; mt < 2; ++mt)
      afc[mt] = *(const bf16x8*)&Hs[(mt * 16 + lr) * 264 + (kt << 5) + lq * 8];
    #pragma unroll
    for (int mt = 0; mt < 2; ++mt)
      #pragma unroll
      for (int nt = 0; nt < 4; ++nt)
        acc[mt][nt] = __builtin_amdgcn_mfma_f32_16x16x32_bf16(afc[mt], bqb[s][nt], acc[mt][nt], 0, 0, 0);
    if (kt + DEPTH < 8) LOADB(W3, kt + DEPTH, bqb[s]);
  }
  // bias
  #pragma unroll
  for (int nt = 0; nt < 4; ++nt) {
    const float bv = b3[wave * 64 + nt * 16 + lr];
    #pragma unroll
    for (int mt = 0; mt < 2; ++mt)
      #pragma unroll
      for (int r = 0; r < 4; ++r)
        acc[mt][nt][r] += bv;
  }
  // LN stats
  #pragma unroll
  for (int mt = 0; mt < 2; ++mt) {
    #pragma unroll
    for (int r = 0; r < 4; ++r) {
      float s1 = 0.f, s2 = 0.f;
      #pragma unroll
      for (int nt = 0; nt < 4; ++nt) {
        float v = acc[mt][nt][r];
        s1 += v; s2 += v * v;
      }
      #pragma unroll
      for (int dlt = 1; dlt < 16; dlt <<= 1) {
        s1 += __shfl_xor(s1, dlt, 64);
        s2 += __shfl_xor(s2, dlt, 64);
      }
      if (lr == 0) {
        ps1[(mt * 16 + lq * 4 + r) * 4 + wave] = s1;
        ps2[(mt * 16 + lq * 4 + r) * 4 + wave] = s2;
      }
    }
  }
  __syncthreads();
  #pragma unroll
  for (int mt = 0; mt < 2; ++mt) {
    #pragma unroll
    for (int r = 0; r < 4; ++r) {
      const int rl = mt * 16 + lq * 4 + r;
      const int row = r0 + rl;
      float fs1 = ps1[rl * 4 + 0] + ps1[rl * 4 + 1] + ps1[rl * 4 + 2] + ps1[rl * 4 + 3];
      float fs2 = ps2[rl * 4 + 0] + ps2[rl * 4 + 1] + ps2[rl * 4 + 2] + ps2[rl * 4 + 3];
      float mean = fs1 * (1.f / 256.f);
      float var  = fs2 * (1.f / 256.f) - mean * mean;
      float rstd = rsqrtf(var + 1e-5f);
      if (row < M) {
        #pragma unroll
        for (int nt = 0; nt < 4; ++nt) {
          const int col = wave * 64 + nt * 16 + lr;
          float v = (acc[mt][nt][r] - mean) * rstd * lng[col] + lnb[col];
          if (resid) {
            float* rp = resid + (size_t)row * D + col;
            float nv = *rp + v;
            *rp = nv;
            if (bfout) bfout[(size_t)row * D + col] = f2bf(nv);
          } else {
            unsigned short* bp = bfout + (size_t)row * D + col;
            *bp = f2bf(bf2f(*bp) + v);
          }
        }
      }
    }
  }
  #undef LOADA
  #undef LOADB
}

extern "C" void kernel_launch(void* const* d_in, const int* in_sizes, int n_in,
                              void* d_out, int out_size, void* d_ws, size_t ws_size,
                              hipStream_t stream) {
  const float* x         = (const float*)d_in[0];
  const int*   eidx      = (const int*)d_in[1];
  const float* edge_attr = (const float*)d_in[2];
  const float* eW1 = (const float*)d_in[3];
  const float* eB1 = (const float*)d_in[4];
  const float* eW2 = (const float*)d_in[5];
  const float* eB2 = (const float*)d_in[6];
  const float* eW3 = (const float*)d_in[7];
  const float* eB3 = (const float*)d_in[8];
  const float* eLNg = (const float*)d_in[9];
  const float* eLNb = (const float*)d_in[10];
  const float* nW1 = (const float*)d_in[11];
  const float* nB1 = (const float*)d_in[12];
  const float* nW2 = (const float*)d_in[13];
  const float* nB2 = (const float*)d_in[14];
  const float* nW3 = (const float*)d_in[15];
  const float* nB3 = (const float*)d_in[16];
  const float* nLNg = (const float*)d_in[17];
  const float* nLNb = (const float*)d_in[18];

  const int Nn = in_sizes[0] / D;   // 10000
  const int E  = in_sizes[1] / 2;   // 60000
  const int B  = in_sizes[4] / D;   // 9

  const int* srcI = eidx;
  const int* dstI = eidx + E;

  char* wsp = (char*)d_ws;
  size_t off = 0;
  auto alloc = [&](size_t bytes) {
    char* p = wsp + off;
    off += (bytes + 255) & ~(size_t)255;
    return p;
  };
  unsigned short* eW1t = (unsigned short*)alloc((size_t)B * 768 * D * 2);
  unsigned short* eW2t = (unsigned short*)alloc((size_t)B * 256 * D * 2);
  unsigned short* eW3t = (unsigned short*)alloc((size_t)B * 256 * D * 2);
  unsigned short* nW1t = (unsigned short*)alloc((size_t)B * 512 * D * 2);
  unsigned short* nW2t = (unsigned short*)alloc((size_t)B * 256 * D * 2);
  unsigned short* nW3t = (unsigned short*)alloc((size_t)B * 256 * D * 2);
  unsigned short* eabf  = (unsigned short*)alloc((size_t)E * D * 2);
  unsigned short* xbf   = (unsigned short*)alloc((size_t)Nn * D * 2);
  unsigned short* aggbf = (unsigned short*)alloc((size_t)Nn * D * 2);
  int*            hist  = (int*)alloc((size_t)(Nn + 1) * 4);
  int*            offs  = (int*)alloc((size_t)(Nn + 1) * 4);
  int*            cnt   = (int*)alloc((size_t)Nn * 4);
  int*            eid   = (int*)alloc((size_t)E * 4);

  float* xbuf = (float*)d_out;  // x state lives in d_out

  auto wp = [&](const float* w, unsigned short* wt, int K) {
    int total = B * K * D;
    wprep_kernel<<<(total + 255) / 256, 256, 0, stream>>>(w, wt, K, total);
  };
  wp(eW1, eW1t, 768);
  wp(eW2, eW2t, 256);
  wp(eW3, eW3t, 256);
  wp(nW1, nW1t, 512);
  wp(nW2, nW2t, 256);
  wp(nW3, nW3t, 256);

  hipMemcpyAsync(xbuf, x, (size_t)Nn * D * 4, hipMemcpyDeviceToDevice, stream);
  {
    int n4 = E * D / 4;
    cvt_bf16_kernel<<<(n4 + 255) / 256, 256, 0, stream>>>(
        (const float4*)edge_attr, (ushort4*)eabf, n4);
    int m4 = Nn * D / 4;
    cvt_bf16_kernel<<<(m4 + 255) / 256, 256, 0, stream>>>(
        (const float4*)x, (ushort4*)xbf, m4);
  }

  // CSR build (edge_index constant across blocks -> once per launch)
  hipMemsetAsync(hist, 0, (size_t)Nn * 4, stream);
  hipMemsetAsync(cnt, 0, (size_t)Nn * 4, stream);
  hist_kernel<<<(E + 255) / 256, 256, 0, stream>>>(dstI, hist, E);
  scan_kernel<<<1, 256, 0, stream>>>(hist, offs, Nn);
  fill_kernel<<<(E + 255) / 256, 256, 0, stream>>>(dstI, offs, cnt, eid, E);

  const int gridE = (E + 31) / 32;
  const int gridN = (Nn + 31) / 32;
  const int gridA = (Nn + 3) / 4;

  for (int b = 0; b < B; ++b) {
    // edge: ea += LN(MLP([x[src], x[dst], ea]))  -- bf16 state RMW in eabf
    fused_mlp<3><<<gridE, 256, 0, stream>>>(
        xbf, srcI, xbf, dstI, eabf,
        eW1t + (size_t)b * 768 * D, eB1 + b * D,
        eW2t + (size_t)b * 256 * D, eB2 + b * D,
        eW3t + (size_t)b * 256 * D, eB3 + b * D,
        eLNg + b * D, eLNb + b * D, nullptr, eabf, E);
    // agg = segment_sum(ea, dst) via CSR gather (bf16 out)
    agg_kernel<<<gridA, 256, 0, stream>>>(eabf, eid, offs, aggbf, Nn);
    // node: x += LN(MLP([x, agg]))  -- fp32 RMW in xbuf + bf16 shadow xbf
    fused_mlp<2><<<gridN, 256, 0, stream>>>(
        xbf, nullptr, aggbf, nullptr, nullptr,
        nW1t + (size_t)b * 512 * D, nB1 + b * D,
        nW2t + (size_t)b * 256 * D, nB2 + b * D,
        nW3t + (size_t)b * 256 * D, nB3 + b * D,
        nLNg + b * D, nLNb + b * D, xbuf, xbf, Nn);
  }
}

// Round 8
// 1383.840 us; speedup vs baseline: 1.1880x; 1.1880x over previous
//
#include <hip/hip_runtime.h>

#define D 256

typedef __attribute__((ext_vector_type(8))) short bf16x8;
typedef __attribute__((ext_vector_type(4))) float f32x4;

__device__ inline unsigned short f2bf(float f) {
  union { float f; unsigned u; } v; v.f = f;
  unsigned r = v.u + 0x7FFFu + ((v.u >> 16) & 1u);
  return (unsigned short)(r >> 16);
}
__device__ inline float bf2f(unsigned short u) {
  union { unsigned u; float f; } v; v.u = ((unsigned)u) << 16;
  return v.f;
}

// async global->LDS, 16B/lane. ldst wave-uniform; data lands at ldst+lane*16.
__device__ inline void gl_lds16(const void* gsrc, void* ldst) {
  __builtin_amdgcn_global_load_lds(
      (const __attribute__((address_space(1))) void*)gsrc,
      (__attribute__((address_space(3))) void*)ldst, 16, 0, 0);
}

// fp32 W[b][k0+k][n] (rows k0..k0+Ksub of a Kfull x 256 matrix) -> bf16
// fragment-major W': W'[((kt*16+ct)*64+lane)*8+j], k=kt*32+(lane>>4)*8+j,
// col=ct*16+(lane&15). A wave's frag for (kt,ct) = contiguous 1KB.
__global__ void wprep_kernel(const float* __restrict__ w, unsigned short* __restrict__ wt,
                             int Kfull, int k0, int Ksub, int total) {
  int idx = blockIdx.x * 256 + threadIdx.x;
  if (idx >= total) return;
  int per_b = Ksub * D;
  int b = idx / per_b;
  int r = idx % per_b;
  int j = r & 7;
  int lane = (r >> 3) & 63;
  int t = r >> 9;            // kt*16 + ct
  int kt = t >> 4, ct = t & 15;
  int k = kt * 32 + (lane >> 4) * 8 + j;
  int col = ct * 16 + (lane & 15);
  wt[idx] = f2bf(w[((size_t)b * Kfull + k0 + k) * D + col]);
}

__global__ void cvt_bf16_kernel(const float4* __restrict__ in, ushort4* __restrict__ out, int n4) {
  int i = blockIdx.x * 256 + threadIdx.x;
  if (i >= n4) return;
  float4 f = in[i];
  ushort4 o;
  o.x = f2bf(f.x); o.y = f2bf(f.y); o.z = f2bf(f.z); o.w = f2bf(f.w);
  out[i] = o;
}

// ---- CSR build ----
__global__ void hist_kernel(const int* __restrict__ dst, int* __restrict__ hist, int E) {
  int i = blockIdx.x * 256 + threadIdx.x;
  if (i < E) atomicAdd(&hist[dst[i]], 1);
}

__global__ void scan_kernel(const int* __restrict__ hist, int* __restrict__ offs, int Nn) {
  __shared__ int part[256];
  int t = threadIdx.x;
  int chunk = (Nn + 255) >> 8;
  int s = t * chunk;
  int e = s + chunk; if (e > Nn) e = Nn; if (s > Nn) s = Nn;
  int sum = 0;
  for (int i = s; i < e; ++i) sum += hist[i];
  part[t] = sum;
  __syncthreads();
  if (t == 0) {
    int run = 0;
    for (int i = 0; i < 256; ++i) { int v = part[i]; part[i] = run; run += v; }
  }
  __syncthreads();
  int run = part[t];
  for (int i = s; i < e; ++i) { offs[i] = run; run += hist[i]; }
  if (e == Nn) offs[Nn] = run;
}

__global__ void fill_kernel(const int* __restrict__ dst, const int* __restrict__ offs,
                            int* __restrict__ cnt, int* __restrict__ eid, int E) {
  int i = blockIdx.x * 256 + threadIdx.x;
  if (i < E) {
    int d = dst[i];
    int p = offs[d] + atomicAdd(&cnt[d], 1);
    eid[p] = i;
  }
}

// agg[node] = sum over CSR bucket of eabf rows (bf16 in, bf16 out). One wave/node.
__global__ __launch_bounds__(256) void agg_kernel(
    const unsigned short* __restrict__ eabf, const int* __restrict__ eid,
    const int* __restrict__ offs, unsigned short* __restrict__ aggbf, int Nn) {
  int node = blockIdx.x * 4 + (threadIdx.x >> 6);
  if (node >= Nn) return;
  int lane = threadIdx.x & 63;
  int s = offs[node], e = offs[node + 1];
  float4 acc = make_float4(0.f, 0.f, 0.f, 0.f);
  for (int i = s; i < e; ++i) {
    int ed = eid[i];
    ushort4 v = *(const ushort4*)(eabf + (size_t)ed * D + lane * 4);
    acc.x += bf2f(v.x); acc.y += bf2f(v.y); acc.z += bf2f(v.z); acc.w += bf2f(v.w);
  }
  ushort4 o;
  o.x = f2bf(acc.x); o.y = f2bf(acc.y); o.z = f2bf(acc.z); o.w = f2bf(acc.w);
  *(ushort4*)(aggbf + (size_t)node * D + lane * 4) = o;
}

// out[M,256] = A[M,256] @ W (frag-major, K=256), bf16 out, no bias.
__global__ __launch_bounds__(256, 4) void gemm32(
    const unsigned short* __restrict__ A, const unsigned short* __restrict__ W,
    unsigned short* __restrict__ out, int M)
{
  const int tid  = threadIdx.x;
  const int lane = tid & 63;
  const int wave = tid >> 6;
  const int lr   = lane & 15;
  const int lq   = lane >> 4;
  const int r0   = blockIdx.x * 32;

  int ro[2];
  #pragma unroll
  for (int mt = 0; mt < 2; ++mt) {
    int rw = r0 + mt * 16 + lr;
    if (rw > M - 1) rw = M - 1;
    ro[mt] = rw * D;
  }
  const int ctb = wave * 4;
  f32x4 acc[2][4];
  #pragma unroll
  for (int i = 0; i < 2; i++)
    #pragma unroll
    for (int j = 0; j < 4; j++)
      acc[i][j] = (f32x4){0.f, 0.f, 0.f, 0.f};

  constexpr int DEPTH = 3;
  bf16x8 afb[DEPTH][2], bqb[DEPTH][4];
  #pragma unroll
  for (int d = 0; d < DEPTH; ++d) {
    #pragma unroll
    for (int mt = 0; mt < 2; ++mt)
      afb[d][mt] = *(const bf16x8*)(A + ro[mt] + (d << 5) + lq * 8);
    #pragma unroll
    for (int nt = 0; nt < 4; ++nt)
      bqb[d][nt] = *(const bf16x8*)(W + (((d * 16 + ctb + nt) * 64 + lane) * 8));
  }
  #pragma unroll
  for (int kt = 0; kt < 8; ++kt) {
    const int s = kt % DEPTH;
    #pragma unroll
    for (int mt = 0; mt < 2; ++mt)
      #pragma unroll
      for (int nt = 0; nt < 4; ++nt)
        acc[mt][nt] = __builtin_amdgcn_mfma_f32_16x16x32_bf16(afb[s][mt], bqb[s][nt], acc[mt][nt], 0, 0, 0);
    if (kt + DEPTH < 8) {
      const int kn = kt + DEPTH;
      #pragma unroll
      for (int mt = 0; mt < 2; ++mt)
        afb[s][mt] = *(const bf16x8*)(A + ro[mt] + (kn << 5) + lq * 8);
      #pragma unroll
      for (int nt = 0; nt < 4; ++nt)
        bqb[s][nt] = *(const bf16x8*)(W + (((kn * 16 + ctb + nt) * 64 + lane) * 8));
    }
  }
  #pragma unroll
  for (int mt = 0; mt < 2; ++mt)
    #pragma unroll
    for (int r = 0; r < 4; ++r) {
      const int row = r0 + mt * 16 + lq * 4 + r;
      if (row < M) {
        #pragma unroll
        for (int nt = 0; nt < 4; ++nt)
          out[(size_t)row * D + wave * 64 + nt * 16 + lr] = f2bf(acc[mt][nt][r]);
      }
    }
}

// Edge MLP with decomposed layer 1:
//   h1 = relu(ea@W1c + U[src] + V[dst] + b1);  h2 = relu(h1@W2+b2);
//   ea += LN(h2@W3+b3)*g+bn     (bf16 state RMW on eabf)
// U/V rows staged to LDS via global_load_lds at kernel start (latency hidden
// behind the ea@W1c GEMM). LDS overlay: UV dead after epilogue-1, Hs after.
__global__ __launch_bounds__(256, 4) void fused_edge(
    unsigned short* __restrict__ eabf,
    const int* __restrict__ src, const int* __restrict__ dst,
    const unsigned short* __restrict__ Ubf, const unsigned short* __restrict__ Vbf,
    const unsigned short* __restrict__ W1c, const float* __restrict__ b1,
    const unsigned short* __restrict__ W2, const float* __restrict__ b2,
    const unsigned short* __restrict__ W3, const float* __restrict__ b3,
    const float* __restrict__ lng, const float* __restrict__ lnb, int E)
{
  __shared__ __align__(16) unsigned short SH[16896];  // 33792 B -> 4 blocks/CU
  unsigned short* Us = SH;            // [32][256] unpadded (gl_lds layout)
  unsigned short* Vs = SH + 8192;     // [32][256]
  unsigned short* Hs = SH;            // [32][264] padded, overlays Us after ep1
  float* ps1 = (float*)(SH + 16384);
  float* ps2 = (float*)(SH + 16384) + 128;

  const int tid  = threadIdx.x;
  const int lane = tid & 63;
  const int wave = tid >> 6;
  const int lr   = lane & 15;
  const int lq   = lane >> 4;
  const int r0   = blockIdx.x * 32;

  // ---- async stage U[src[row]], V[dst[row]] rows -> LDS (4+4 calls/wave)
  #pragma unroll
  for (int c = 0; c < 4; ++c) {
    int row = wave * 8 + c * 2 + (lane >> 5);
    int er = r0 + row; if (er > E - 1) er = E - 1;
    int colel = (lane & 31) * 8;
    gl_lds16(Ubf + (size_t)src[er] * D + colel, Us + wave * 2048 + c * 512);
    gl_lds16(Vbf + (size_t)dst[er] * D + colel, Vs + wave * 2048 + c * 512);
  }

  int ro[2];
  #pragma unroll
  for (int mt = 0; mt < 2; ++mt) {
    int rw = r0 + mt * 16 + lr;
    if (rw > E - 1) rw = E - 1;
    ro[mt] = rw * D;
  }
  const int ctb = wave * 4;
  #define LOADB(Wp, kt, dst_)                                                 \
    _Pragma("unroll")                                                         \
    for (int nt = 0; nt < 4; ++nt)                                            \
      dst_[nt] = *(const bf16x8*)((Wp) + ((((kt) * 16 + ctb + nt) * 64 + lane) * 8));

  f32x4 acc[2][4];
  constexpr int DEPTH = 3;
  bf16x8 afb[DEPTH][2], bqb[DEPTH][4];

  // ---------------- Layer 1: ea @ W1c (8 K-tiles) ----------------
  #pragma unroll
  for (int i = 0; i < 2; i++)
    #pragma unroll
    for (int j = 0; j < 4; j++)
      acc[i][j] = (f32x4){0.f, 0.f, 0.f, 0.f};
  #pragma unroll
  for (int d = 0; d < DEPTH; ++d) {
    #pragma unroll
    for (int mt = 0; mt < 2; ++mt)
      afb[d][mt] = *(const bf16x8*)(eabf + ro[mt] + (d << 5) + lq * 8);
    LOADB(W1c, d, bqb[d]);
  }
  #pragma unroll
  for (int kt = 0; kt < 8; ++kt) {
    const int s = kt % DEPTH;
    #pragma unroll
    for (int mt = 0; mt < 2; ++mt)
      #pragma unroll
      for (int nt = 0; nt < 4; ++nt)
        acc[mt][nt] = __builtin_amdgcn_mfma_f32_16x16x32_bf16(afb[s][mt], bqb[s][nt], acc[mt][nt], 0, 0, 0);
    if (kt + DEPTH < 8) {
      const int kn = kt + DEPTH;
      #pragma unroll
      for (int mt = 0; mt < 2; ++mt)
        afb[s][mt] = *(const bf16x8*)(eabf + ro[mt] + (kn << 5) + lq * 8);
      LOADB(W1c, kn, bqb[s]);
    }
  }
  __syncthreads();   // UV staged (vmcnt drained) + visible across waves

  // epilogue 1: acc += U[src] + V[dst] + b1, relu (kept in regs)
  {
    float bv[4];
    #pragma unroll
    for (int nt = 0; nt < 4; ++nt) bv[nt] = b1[wave * 64 + nt * 16 + lr];
    #pragma unroll
    for (int mt = 0; mt < 2; ++mt)
      #pragma unroll
      for (int r = 0; r < 4; ++r) {
        const int row = mt * 16 + lq * 4 + r;
        #pragma unroll
        for (int nt = 0; nt < 4; ++nt) {
          const int col = wave * 64 + nt * 16 + lr;
          float v = acc[mt][nt][r] + bv[nt]
                  + bf2f(Us[row * 256 + col]) + bf2f(Vs[row * 256 + col]);
          acc[mt][nt][r] = v > 0.f ? v : 0.f;
        }
      }
  }
  __syncthreads();   // all UV reads done before Hs overlay write
  #pragma unroll
  for (int mt = 0; mt < 2; ++mt)
    #pragma unroll
    for (int r = 0; r < 4; ++r) {
      const int row = mt * 16 + lq * 4 + r;
      #pragma unroll
      for (int nt = 0; nt < 4; ++nt)
        Hs[row * 264 + wave * 64 + nt * 16 + lr] = f2bf(acc[mt][nt][r]);
    }
  __syncthreads();   // h1 visible

  // ---------------- Layer 2 (K=256, A from Hs) ----------------
  #pragma unroll
  for (int i = 0; i < 2; i++)
    #pragma unroll
    for (int j = 0; j < 4; j++)
      acc[i][j] = (f32x4){0.f, 0.f, 0.f, 0.f};
  #pragma unroll
  for (int d = 0; d < DEPTH; ++d) LOADB(W2, d, bqb[d]);
  #pragma unroll
  for (int kt = 0; kt < 8; ++kt) {
    const int s = kt % DEPTH;
    bf16x8 afc[2];
    #pragma unroll
    for (int mt = 0; mt < 2; ++mt)
      afc[mt] = *(const bf16x8*)&Hs[(mt * 16 + lr) * 264 + (kt << 5) + lq * 8];
    #pragma unroll
    for (int mt = 0; mt < 2; ++mt)
      #pragma unroll
      for (int nt = 0; nt < 4; ++nt)
        acc[mt][nt] = __builtin_amdgcn_mfma_f32_16x16x32_bf16(afc[mt], bqb[s][nt], acc[mt][nt], 0, 0, 0);
    if (kt + DEPTH < 8) LOADB(W2, kt + DEPTH, bqb[s]);
  }
  __syncthreads();
  {
    float bv[4];
    #pragma unroll
    for (int nt = 0; nt < 4; ++nt) bv[nt] = b2[wave * 64 + nt * 16 + lr];
    #pragma unroll
    for (int mt = 0; mt < 2; ++mt)
      #pragma unroll
      for (int r = 0; r < 4; ++r) {
        const int row = mt * 16 + lq * 4 + r;
        #pragma unroll
        for (int nt = 0; nt < 4; ++nt) {
          float v = acc[mt][nt][r] + bv[nt];
          v = v > 0.f ? v : 0.f;
          Hs[row * 264 + wave * 64 + nt * 16 + lr] = f2bf(v);
        }
      }
  }
  __syncthreads();

  // ---------------- Layer 3 (K=256) + LN + residual ----------------
  #pragma unroll
  for (int i = 0; i < 2; i++)
    #pragma unroll
    for (int j = 0; j < 4; j++)
      acc[i][j] = (f32x4){0.f, 0.f, 0.f, 0.f};
  #pragma unroll
  for (int d = 0; d < DEPTH; ++d) LOADB(W3, d, bqb[d]);
  #pragma unroll
  for (int kt = 0; kt < 8; ++kt) {
    const int s = kt % DEPTH;
    bf16x8 afc[2];
    #pragma unroll
    for (int mt = 0; mt < 2; ++mt)
      afc[mt] = *(const bf16x8*)&Hs[(mt * 16 + lr) * 264 + (kt << 5) + lq * 8];
    #pragma unroll
    for (int mt = 0; mt < 2; ++mt)
      #pragma unroll
      for (int nt = 0; nt < 4; ++nt)
        acc[mt][nt] = __builtin_amdgcn_mfma_f32_16x16x32_bf16(afc[mt], bqb[s][nt], acc[mt][nt], 0, 0, 0);
    if (kt + DEPTH < 8) LOADB(W3, kt + DEPTH, bqb[s]);
  }
  #pragma unroll
  for (int nt = 0; nt < 4; ++nt) {
    const float bv = b3[wave * 64 + nt * 16 + lr];
    #pragma unroll
    for (int mt = 0; mt < 2; ++mt)
      #pragma unroll
      for (int r = 0; r < 4; ++r)
        acc[mt][nt][r] += bv;
  }
  #pragma unroll
  for (int mt = 0; mt < 2; ++mt) {
    #pragma unroll
    for (int r = 0; r < 4; ++r) {
      float s1 = 0.f, s2 = 0.f;
      #pragma unroll
      for (int nt = 0; nt < 4; ++nt) {
        float v = acc[mt][nt][r];
        s1 += v; s2 += v * v;
      }
      #pragma unroll
      for (int dlt = 1; dlt < 16; dlt <<= 1) {
        s1 += __shfl_xor(s1, dlt, 64);
        s2 += __shfl_xor(s2, dlt, 64);
      }
      if (lr == 0) {
        ps1[(mt * 16 + lq * 4 + r) * 4 + wave] = s1;
        ps2[(mt * 16 + lq * 4 + r) * 4 + wave] = s2;
      }
    }
  }
  __syncthreads();
  #pragma unroll
  for (int mt = 0; mt < 2; ++mt) {
    #pragma unroll
    for (int r = 0; r < 4; ++r) {
      const int rl = mt * 16 + lq * 4 + r;
      const int row = r0 + rl;
      float fs1 = ps1[rl * 4 + 0] + ps1[rl * 4 + 1] + ps1[rl * 4 + 2] + ps1[rl * 4 + 3];
      float fs2 = ps2[rl * 4 + 0] + ps2[rl * 4 + 1] + ps2[rl * 4 + 2] + ps2[rl * 4 + 3];
      float mean = fs1 * (1.f / 256.f);
      float var  = fs2 * (1.f / 256.f) - mean * mean;
      float rstd = rsqrtf(var + 1e-5f);
      if (row < E) {
        #pragma unroll
        for (int nt = 0; nt < 4; ++nt) {
          const int col = wave * 64 + nt * 16 + lr;
          float v = (acc[mt][nt][r] - mean) * rstd * lng[col] + lnb[col];
          unsigned short* bp = eabf + (size_t)row * D + col;
          *bp = f2bf(bf2f(*bp) + v);
        }
      }
    }
  }
  #undef LOADB
}

// Node MLP (unchanged from r7): x += LN(MLP([x, agg])) with fp32 resid + bf16 shadow
template<int NCHUNK>
__global__ __launch_bounds__(256, 4) void fused_mlp(
    const unsigned short* __restrict__ C0, const int* __restrict__ g0,
    const unsigned short* __restrict__ C1, const int* __restrict__ g1,
    const unsigned short* __restrict__ C2,
    const unsigned short* __restrict__ W1, const float* __restrict__ b1,
    const unsigned short* __restrict__ W2, const float* __restrict__ b2,
    const unsigned short* __restrict__ W3, const float* __restrict__ b3,
    const float* __restrict__ lng, const float* __restrict__ lnb,
    float* __restrict__ resid, unsigned short* __restrict__ bfout, int M)
{
  __shared__ __align__(16) unsigned short Hs[32 * 264];
  __shared__ float ps1[128];
  __shared__ float ps2[128];

  const int tid  = threadIdx.x;
  const int lane = tid & 63;
  const int wave = tid >> 6;
  const int lr   = lane & 15;
  const int lq   = lane >> 4;
  const int r0   = blockIdx.x * 32;

  int ro0[2], ro1[2], ro2[2];
  #pragma unroll
  for (int mt = 0; mt < 2; ++mt) {
    int rw = r0 + mt * 16 + lr;
    if (rw > M - 1) rw = M - 1;
    ro0[mt] = (g0 ? g0[rw] : rw) * D;
    ro1[mt] = (NCHUNK > 1) ? ((g1 ? g1[rw] : rw) * D) : 0;
    ro2[mt] = (NCHUNK > 2) ? rw * D : 0;
  }

  f32x4 acc[2][4];
  const int ctb = wave * 4;
  #define LOADB(Wp, kt, dst)                                                  \
    _Pragma("unroll")                                                         \
    for (int nt = 0; nt < 4; ++nt)                                            \
      dst[nt] = *(const bf16x8*)((Wp) + ((((kt) * 16 + ctb + nt) * 64 + lane) * 8));
  #define LOADA(kt, dst) {                                                    \
    const int c_ = (kt) >> 3;                                                 \
    const int koff_ = (((kt) & 7) << 5) + lq * 8;                             \
    const unsigned short* bp_ = (c_ == 0) ? C0 : (c_ == 1 ? C1 : C2);         \
    _Pragma("unroll")                                                         \
    for (int mt = 0; mt < 2; ++mt) {                                          \
      int r_ = ro0[mt];                                                       \
      if (NCHUNK > 1 && c_ == 1) r_ = ro1[mt];                                \
      if (NCHUNK > 2 && c_ == 2) r_ = ro2[mt];                                \
      dst[mt] = *(const bf16x8*)(bp_ + r_ + koff_);                           \
    }                                                                         \
  }

  constexpr int DEPTH = 3;
  bf16x8 afb[DEPTH][2], bqb[DEPTH][4];

  #pragma unroll
  for (int i = 0; i < 2; i++)
    #pragma unroll
    for (int j = 0; j < 4; j++)
      acc[i][j] = (f32x4){0.f, 0.f, 0.f, 0.f};

  constexpr int NKT = NCHUNK * 8;
  #pragma unroll
  for (int d = 0; d < DEPTH; ++d) {
    LOADA(d, afb[d]);
    LOADB(W1, d, bqb[d]);
  }
  #pragma unroll
  for (int kt = 0; kt < NKT; ++kt) {
    const int s = kt % DEPTH;
    #pragma unroll
    for (int mt = 0; mt < 2; ++mt)
      #pragma unroll
      for (int nt = 0; nt < 4; ++nt)
        acc[mt][nt] = __builtin_amdgcn_mfma_f32_16x16x32_bf16(afb[s][mt], bqb[s][nt], acc[mt][nt], 0, 0, 0);
    if (kt + DEPTH < NKT) {
      LOADA(kt + DEPTH, afb[s]);
      LOADB(W1, kt + DEPTH, bqb[s]);
    }
  }
  {
    float bv[4];
    #pragma unroll
    for (int nt = 0; nt < 4; ++nt) bv[nt] = b1[wave * 64 + nt * 16 + lr];
    #pragma unroll
    for (int mt = 0; mt < 2; ++mt)
      #pragma unroll
      for (int r = 0; r < 4; ++r) {
        const int row = mt * 16 + lq * 4 + r;
        #pragma unroll
        for (int nt = 0; nt < 4; ++nt) {
          float v = acc[mt][nt][r] + bv[nt];
          v = v > 0.f ? v : 0.f;
          Hs[row * 264 + wave * 64 + nt * 16 + lr] = f2bf(v);
        }
      }
  }
  __syncthreads();

  #pragma unroll
  for (int i = 0; i < 2; i++)
    #pragma unroll
    for (int j = 0; j < 4; j++)
      acc[i][j] = (f32x4){0.f, 0.f, 0.f, 0.f};
  #pragma unroll
  for (int d = 0; d < DEPTH; ++d) LOADB(W2, d, bqb[d]);
  #pragma unroll
  for (int kt = 0; kt < 8; ++kt) {
    const int s = kt % DEPTH;
    bf16x8 afc[2];
    #pragma unroll
    for (int mt = 0; mt < 2; ++mt)
      afc[mt] = *(const bf16x8*)&Hs[(mt * 16 + lr) * 264 + (kt << 5) + lq * 8];
    #pragma unroll
    for (int mt = 0; mt < 2; ++mt)
      #pragma unroll
      for (int nt = 0; nt < 4; ++nt)
        acc[mt][nt] = __builtin_amdgcn_mfma_f32_16x16x32_bf16(afc[mt], bqb[s][nt], acc[mt][nt], 0, 0, 0);
    if (kt + DEPTH < 8) LOADB(W2, kt + DEPTH, bqb[s]);
  }
  __syncthreads();
  {
    float bv[4];
    #pragma unroll
    for (int nt = 0; nt < 4; ++nt) bv[nt] = b2[wave * 64 + nt * 16 + lr];
    #pragma unroll
    for (int mt = 0; mt < 2; ++mt)
      #pragma unroll
      for (int r = 0; r < 4; ++r) {
        const int row = mt * 16 + lq * 4 + r;
        #pragma unroll
        for (int nt = 0; nt < 4; ++nt) {
          float v = acc[mt][nt][r] + bv[nt];
          v = v > 0.f ? v : 0.f;
          Hs[row * 264 + wave * 64 + nt * 16 + lr] = f2bf(v);
        }
      }
  }
  __syncthreads();

  #pragma unroll
  for (int i = 0; i < 2; i++)
    #pragma unroll
    for (int j = 0; j < 4; j++)
      acc[i][j] = (f32x4){0.f, 0.f, 0.f, 0.f};
  #pragma unroll
  for (int d = 0; d < DEPTH; ++d) LOADB(W3, d, bqb[d]);
  #pragma unroll
  for (int kt = 0; kt < 8; ++kt) {
    const int s = kt % DEPTH;
    bf16x8 afc[2];
    #pragma unroll
    for (int mt = 0; mt < 2; ++mt)
      afc[mt] = *(const bf16x8*)&Hs[(mt * 16 + lr) * 264 + (kt << 5) + lq * 8];
    #pragma unroll
    for (int mt = 0; mt < 2; ++mt)
      #pragma unroll
      for (int nt = 0; nt < 4; ++nt)
        acc[mt][nt] = __builtin_amdgcn_mfma_f32_16x16x32_bf16(afc[mt], bqb[s][nt], acc[mt][nt], 0, 0, 0);
    if (kt + DEPTH < 8) LOADB(W3, kt + DEPTH, bqb[s]);
  }
  #pragma unroll
  for (int nt = 0; nt < 4; ++nt) {
    const float bv = b3[wave * 64 + nt * 16 + lr];
    #pragma unroll
    for (int mt = 0; mt < 2; ++mt)
      #pragma unroll
      for (int r = 0; r < 4; ++r)
        acc[mt][nt][r] += bv;
  }
  #pragma unroll
  for (int mt = 0; mt < 2; ++mt) {
    #pragma unroll
    for (int r = 0; r < 4; ++r) {
      float s1 = 0.f, s2 = 0.f;
      #pragma unroll
      for (int nt = 0; nt < 4; ++nt) {
        float v = acc[mt][nt][r];
        s1 += v; s2 += v * v;
      }
      #pragma unroll
      for (int dlt = 1; dlt < 16; dlt <<= 1) {
        s1 += __shfl_xor(s1, dlt, 64);
        s2 += __shfl_xor(s2, dlt, 64);
      }
      if (lr == 0) {
        ps1[(mt * 16 + lq * 4 + r) * 4 + wave] = s1;
        ps2[(mt * 16 + lq * 4 + r) * 4 + wave] = s2;
      }
    }
  }
  __syncthreads();
  #pragma unroll
  for (int mt = 0; mt < 2; ++mt) {
    #pragma unroll
    for (int r = 0; r < 4; ++r) {
      const int rl = mt * 16 + lq * 4 + r;
      const int row = r0 + rl;
      float fs1 = ps1[rl * 4 + 0] + ps1[rl * 4 + 1] + ps1[rl * 4 + 2] + ps1[rl * 4 + 3];
      float fs2 = ps2[rl * 4 + 0] + ps2[rl * 4 + 1] + ps2[rl * 4 + 2] + ps2[rl * 4 + 3];
      float mean = fs1 * (1.f / 256.f);
      float var  = fs2 * (1.f / 256.f) - mean * mean;
      float rstd = rsqrtf(var + 1e-5f);
      if (row < M) {
        #pragma unroll
        for (int nt = 0; nt < 4; ++nt) {
          const int col = wave * 64 + nt * 16 + lr;
          float v = (acc[mt][nt][r] - mean) * rstd * lng[col] + lnb[col];
          if (resid) {
            float* rp = resid + (size_t)row * D + col;
            float nv = *rp + v;
            *rp = nv;
            if (bfout) bfout[(size_t)row * D + col] = f2bf(nv);
          } else {
            unsigned short* bp = bfout + (size_t)row * D + col;
            *bp = f2bf(bf2f(*bp) + v);
          }
        }
      }
    }
  }
  #undef LOADA
  #undef LOADB
}

extern "C" void kernel_launch(void* const* d_in, const int* in_sizes, int n_in,
                              void* d_out, int out_size, void* d_ws, size_t ws_size,
                              hipStream_t stream) {
  const float* x         = (const float*)d_in[0];
  const int*   eidx      = (const int*)d_in[1];
  const float* edge_attr = (const float*)d_in[2];
  const float* eW1 = (const float*)d_in[3];
  const float* eB1 = (const float*)d_in[4];
  const float* eW2 = (const float*)d_in[5];
  const float* eB2 = (const float*)d_in[6];
  const float* eW3 = (const float*)d_in[7];
  const float* eB3 = (const float*)d_in[8];
  const float* eLNg = (const float*)d_in[9];
  const float* eLNb = (const float*)d_in[10];
  const float* nW1 = (const float*)d_in[11];
  const float* nB1 = (const float*)d_in[12];
  const float* nW2 = (const float*)d_in[13];
  const float* nB2 = (const float*)d_in[14];
  const float* nW3 = (const float*)d_in[15];
  const float* nB3 = (const float*)d_in[16];
  const float* nLNg = (const float*)d_in[17];
  const float* nLNb = (const float*)d_in[18];

  const int Nn = in_sizes[0] / D;   // 10000
  const int E  = in_sizes[1] / 2;   // 60000
  const int B  = in_sizes[4] / D;   // 9

  const int* srcI = eidx;
  const int* dstI = eidx + E;

  char* wsp = (char*)d_ws;
  size_t off = 0;
  auto alloc = [&](size_t bytes) {
    char* p = wsp + off;
    off += (bytes + 255) & ~(size_t)255;
    return p;
  };
  unsigned short* eW1at = (unsigned short*)alloc((size_t)B * 256 * D * 2);
  unsigned short* eW1bt = (unsigned short*)alloc((size_t)B * 256 * D * 2);
  unsigned short* eW1ct = (unsigned short*)alloc((size_t)B * 256 * D * 2);
  unsigned short* eW2t  = (unsigned short*)alloc((size_t)B * 256 * D * 2);
  unsigned short* eW3t  = (unsigned short*)alloc((size_t)B * 256 * D * 2);
  unsigned short* nW1t  = (unsigned short*)alloc((size_t)B * 512 * D * 2);
  unsigned short* nW2t  = (unsigned short*)alloc((size_t)B * 256 * D * 2);
  unsigned short* nW3t  = (unsigned short*)alloc((size_t)B * 256 * D * 2);
  unsigned short* eabf  = (unsigned short*)alloc((size_t)E * D * 2);
  unsigned short* xbf   = (unsigned short*)alloc((size_t)Nn * D * 2);
  unsigned short* aggbf = (unsigned short*)alloc((size_t)Nn * D * 2);
  unsigned short* Ubf   = (unsigned short*)alloc((size_t)Nn * D * 2);
  unsigned short* Vbf   = (unsigned short*)alloc((size_t)Nn * D * 2);
  int*            hist  = (int*)alloc((size_t)(Nn + 1) * 4);
  int*            offs  = (int*)alloc((size_t)(Nn + 1) * 4);
  int*            cnt   = (int*)alloc((size_t)Nn * 4);
  int*            eid   = (int*)alloc((size_t)E * 4);

  float* xbuf = (float*)d_out;  // x state lives in d_out

  auto wp = [&](const float* w, unsigned short* wt, int Kfull, int k0, int Ksub) {
    int total = B * Ksub * D;
    wprep_kernel<<<(total + 255) / 256, 256, 0, stream>>>(w, wt, Kfull, k0, Ksub, total);
  };
  wp(eW1, eW1at, 768, 0, 256);
  wp(eW1, eW1bt, 768, 256, 256);
  wp(eW1, eW1ct, 768, 512, 256);
  wp(eW2, eW2t, 256, 0, 256);
  wp(eW3, eW3t, 256, 0, 256);
  wp(nW1, nW1t, 512, 0, 512);
  wp(nW2, nW2t, 256, 0, 256);
  wp(nW3, nW3t, 256, 0, 256);

  hipMemcpyAsync(xbuf, x, (size_t)Nn * D * 4, hipMemcpyDeviceToDevice, stream);
  {
    int n4 = E * D / 4;
    cvt_bf16_kernel<<<(n4 + 255) / 256, 256, 0, stream>>>(
        (const float4*)edge_attr, (ushort4*)eabf, n4);
    int m4 = Nn * D / 4;
    cvt_bf16_kernel<<<(m4 + 255) / 256, 256, 0, stream>>>(
        (const float4*)x, (ushort4*)xbf, m4);
  }

  // CSR build (edge_index constant across blocks -> once per launch)
  hipMemsetAsync(hist, 0, (size_t)Nn * 4, stream);
  hipMemsetAsync(cnt, 0, (size_t)Nn * 4, stream);
  hist_kernel<<<(E + 255) / 256, 256, 0, stream>>>(dstI, hist, E);
  scan_kernel<<<1, 256, 0, stream>>>(hist, offs, Nn);
  fill_kernel<<<(E + 255) / 256, 256, 0, stream>>>(dstI, offs, cnt, eid, E);

  const int gridE = (E + 31) / 32;
  const int gridN = (Nn + 31) / 32;
  const int gridA = (Nn + 3) / 4;

  for (int b = 0; b < B; ++b) {
    // U = x@W1a, V = x@W1b  (dense, gather-free)
    gemm32<<<gridN, 256, 0, stream>>>(xbf, eW1at + (size_t)b * 256 * D, Ubf, Nn);
    gemm32<<<gridN, 256, 0, stream>>>(xbf, eW1bt + (size_t)b * 256 * D, Vbf, Nn);
    // edge: ea += LN(MLP(U[src]+V[dst]+ea@W1c))  -- bf16 state RMW in eabf
    fused_edge<<<gridE, 256, 0, stream>>>(
        eabf, srcI, dstI, Ubf, Vbf,
        eW1ct + (size_t)b * 256 * D, eB1 + b * D,
        eW2t + (size_t)b * 256 * D, eB2 + b * D,
        eW3t + (size_t)b * 256 * D, eB3 + b * D,
        eLNg + b * D, eLNb + b * D, E);
    // agg = segment_sum(ea, dst) via CSR gather (bf16 out)
    agg_kernel<<<gridA, 256, 0, stream>>>(eabf, eid, offs, aggbf, Nn);
    // node: x += LN(MLP([x, agg]))  -- fp32 RMW in xbuf + bf16 shadow xbf
    fused_mlp<2><<<gridN, 256, 0, stream>>>(
        xbf, nullptr, aggbf, nullptr, nullptr,
        nW1t + (size_t)b * 512 * D, nB1 + b * D,
        nW2t + (size_t)b * 256 * D, nB2 + b * D,
        nW3t + (size_t)b * 256 * D, nB3 + b * D,
        nLNg + b * D, nLNb + b * D, xbuf, xbf, Nn);
  }
}

// Round 9
// 1227.532 us; speedup vs baseline: 1.3393x; 1.1273x over previous
//
#include <hip/hip_runtime.h>

#define D 256

typedef __attribute__((ext_vector_type(8))) short bf16x8;
typedef __attribute__((ext_vector_type(4))) float f32x4;

__device__ inline unsigned short f2bf(float f) {
  union { float f; unsigned u; } v; v.f = f;
  unsigned r = v.u + 0x7FFFu + ((v.u >> 16) & 1u);
  return (unsigned short)(r >> 16);
}
__device__ inline float bf2f(unsigned short u) {
  union { unsigned u; float f; } v; v.u = ((unsigned)u) << 16;
  return v.f;
}

// async global->LDS, 16B/lane. ldst wave-uniform; data lands at ldst+lane*16.
__device__ inline void gl_lds16(const void* gsrc, void* ldst) {
  __builtin_amdgcn_global_load_lds(
      (const __attribute__((address_space(1))) void*)gsrc,
      (__attribute__((address_space(3))) void*)ldst, 16, 0, 0);
}

// fp32 W[b][k0+k][n] (rows k0..k0+Ksub of Kfull x 256) -> bf16 fragment-major:
// W'[((kt*16+ct)*64+lane)*8+j], k=kt*32+(lane>>4)*8+j, col=ct*16+(lane&15).
__global__ void wprep_kernel(const float* __restrict__ w, unsigned short* __restrict__ wt,
                             int Kfull, int k0, int Ksub, int total) {
  int idx = blockIdx.x * 256 + threadIdx.x;
  if (idx >= total) return;
  int per_b = Ksub * D;
  int b = idx / per_b;
  int r = idx % per_b;
  int j = r & 7;
  int lane = (r >> 3) & 63;
  int t = r >> 9;            // kt*16 + ct
  int kt = t >> 4, ct = t & 15;
  int k = kt * 32 + (lane >> 4) * 8 + j;
  int col = ct * 16 + (lane & 15);
  wt[idx] = f2bf(w[((size_t)b * Kfull + k0 + k) * D + col]);
}

__global__ void cvt_bf16_kernel(const float4* __restrict__ in, ushort4* __restrict__ out, int n4) {
  int i = blockIdx.x * 256 + threadIdx.x;
  if (i >= n4) return;
  float4 f = in[i];
  ushort4 o;
  o.x = f2bf(f.x); o.y = f2bf(f.y); o.z = f2bf(f.z); o.w = f2bf(f.w);
  out[i] = o;
}

// ---- CSR build ----
__global__ void hist_kernel(const int* __restrict__ dst, int* __restrict__ hist, int E) {
  int i = blockIdx.x * 256 + threadIdx.x;
  if (i < E) atomicAdd(&hist[dst[i]], 1);
}

__global__ void scan_kernel(const int* __restrict__ hist, int* __restrict__ offs, int Nn) {
  __shared__ int part[256];
  int t = threadIdx.x;
  int chunk = (Nn + 255) >> 8;
  int s = t * chunk;
  int e = s + chunk; if (e > Nn) e = Nn; if (s > Nn) s = Nn;
  int sum = 0;
  for (int i = s; i < e; ++i) sum += hist[i];
  part[t] = sum;
  __syncthreads();
  if (t == 0) {
    int run = 0;
    for (int i = 0; i < 256; ++i) { int v = part[i]; part[i] = run; run += v; }
  }
  __syncthreads();
  int run = part[t];
  for (int i = s; i < e; ++i) { offs[i] = run; run += hist[i]; }
  if (e == Nn) offs[Nn] = run;
}

__global__ void fill_kernel(const int* __restrict__ dst, const int* __restrict__ offs,
                            int* __restrict__ cnt, int* __restrict__ eid, int E) {
  int i = blockIdx.x * 256 + threadIdx.x;
  if (i < E) {
    int d = dst[i];
    int p = offs[d] + atomicAdd(&cnt[d], 1);
    eid[p] = i;
  }
}

// agg[node] = sum over CSR bucket of eabf rows (bf16 in, bf16 out). One wave/node.
__global__ __launch_bounds__(256) void agg_kernel(
    const unsigned short* __restrict__ eabf, const int* __restrict__ eid,
    const int* __restrict__ offs, unsigned short* __restrict__ aggbf, int Nn) {
  int node = blockIdx.x * 4 + (threadIdx.x >> 6);
  if (node >= Nn) return;
  int lane = threadIdx.x & 63;
  int s = offs[node], e = offs[node + 1];
  float4 acc = make_float4(0.f, 0.f, 0.f, 0.f);
  for (int i = s; i < e; ++i) {
    int ed = eid[i];
    ushort4 v = *(const ushort4*)(eabf + (size_t)ed * D + lane * 4);
    acc.x += bf2f(v.x); acc.y += bf2f(v.y); acc.z += bf2f(v.z); acc.w += bf2f(v.w);
  }
  ushort4 o;
  o.x = f2bf(acc.x); o.y = f2bf(acc.y); o.z = f2bf(acc.z); o.w = f2bf(acc.w);
  *(ushort4*)(aggbf + (size_t)node * D + lane * 4) = o;
}

// U = A@Wa, V = A@Wb (16-row tiles; even blocks->U, odd->V). K=256, bf16 out.
__global__ __launch_bounds__(256, 4) void gemm_uv(
    const unsigned short* __restrict__ A,
    const unsigned short* __restrict__ Wa, const unsigned short* __restrict__ Wb,
    unsigned short* __restrict__ U, unsigned short* __restrict__ V, int M)
{
  const int u    = blockIdx.x & 1;
  const int r0   = (blockIdx.x >> 1) * 16;
  const unsigned short* W = u ? Wb : Wa;
  unsigned short* out = u ? V : U;

  const int tid  = threadIdx.x;
  const int lane = tid & 63;
  const int wave = tid >> 6;
  const int lr   = lane & 15;
  const int lq   = lane >> 4;

  int rw = r0 + lr; if (rw > M - 1) rw = M - 1;
  const int ro = rw * D;
  const int ctb = wave * 4;

  f32x4 acc[4];
  #pragma unroll
  for (int j = 0; j < 4; j++) acc[j] = (f32x4){0.f, 0.f, 0.f, 0.f};

  constexpr int DEPTH = 3;
  bf16x8 afb[DEPTH], bqb[DEPTH][4];
  #pragma unroll
  for (int d = 0; d < DEPTH; ++d) {
    afb[d] = *(const bf16x8*)(A + ro + (d << 5) + lq * 8);
    #pragma unroll
    for (int nt = 0; nt < 4; ++nt)
      bqb[d][nt] = *(const bf16x8*)(W + (((d * 16 + ctb + nt) * 64 + lane) * 8));
  }
  #pragma unroll
  for (int kt = 0; kt < 8; ++kt) {
    const int s = kt % DEPTH;
    #pragma unroll
    for (int nt = 0; nt < 4; ++nt)
      acc[nt] = __builtin_amdgcn_mfma_f32_16x16x32_bf16(afb[s], bqb[s][nt], acc[nt], 0, 0, 0);
    if (kt + DEPTH < 8) {
      const int kn = kt + DEPTH;
      afb[s] = *(const bf16x8*)(A + ro + (kn << 5) + lq * 8);
      #pragma unroll
      for (int nt = 0; nt < 4; ++nt)
        bqb[s][nt] = *(const bf16x8*)(W + (((kn * 16 + ctb + nt) * 64 + lane) * 8));
    }
  }
  #pragma unroll
  for (int r = 0; r < 4; ++r) {
    const int row = r0 + lq * 4 + r;
    if (row < M) {
      #pragma unroll
      for (int nt = 0; nt < 4; ++nt)
        out[(size_t)row * D + wave * 64 + nt * 16 + lr] = f2bf(acc[nt][r]);
    }
  }
}

// Edge MLP, decomposed layer 1, LDS-staged ea tile + coalesced RMW writeback:
//   h1 = relu(ea@W1c + U[src] + V[dst] + b1); h2 = relu(h1@W2+b2)
//   ea += LN(h2@W3+b3)*g+bn    (bf16 state in eabf)
__global__ __launch_bounds__(256, 4) void fused_edge(
    unsigned short* __restrict__ eabf,
    const int* __restrict__ src, const int* __restrict__ dst,
    const unsigned short* __restrict__ Ubf, const unsigned short* __restrict__ Vbf,
    const unsigned short* __restrict__ W1c, const float* __restrict__ b1,
    const unsigned short* __restrict__ W2, const float* __restrict__ b2,
    const unsigned short* __restrict__ W3, const float* __restrict__ b3,
    const float* __restrict__ lng, const float* __restrict__ lnb, int E)
{
  // 24832 shorts = 49664 B -> 3 blocks/CU.
  // region1 [0,8448): eaS (live: stage..L1 end) / Hs (live: post-ep1..copyout)
  // region2 [8448,24832): Us,Vs (live: stage..ep1) / ps (live: LN epilogue)
  __shared__ __align__(16) unsigned short SH[24832];
  unsigned short* eaS = SH;                 // [32][264]
  unsigned short* Hs  = SH;                 // [32][264] overlays eaS
  unsigned short* Us  = SH + 8448;          // [32][256] unpadded (gl_lds)
  unsigned short* Vs  = SH + 8448 + 8192;   // [32][256]
  float* ps1 = (float*)(SH + 8448);         // overlays Us (dead after ep1)
  float* ps2 = (float*)(SH + 8448) + 128;

  const int tid  = threadIdx.x;
  const int lane = tid & 63;
  const int wave = tid >> 6;
  const int lr   = lane & 15;
  const int lq   = lane >> 4;
  const int r0   = blockIdx.x * 32;

  // ---- stage ea tile (coalesced 16B/lane) -> padded eaS
  #pragma unroll
  for (int i = 0; i < 4; ++i) {
    int row = i * 8 + (tid >> 5);
    int cs  = (tid & 31) * 8;
    int er = r0 + row; if (er > E - 1) er = E - 1;
    uint4 v = *(const uint4*)(eabf + (size_t)er * D + cs);
    *(uint4*)&eaS[row * 264 + cs] = v;
  }
  __syncthreads();   // eaS ready

  // ---- async UV row gathers -> LDS (overlap the L1 GEMM)
  #pragma unroll
  for (int c = 0; c < 4; ++c) {
    int row = wave * 8 + c * 2 + (lane >> 5);
    int er = r0 + row; if (er > E - 1) er = E - 1;
    int colel = (lane & 31) * 8;
    gl_lds16(Ubf + (size_t)src[er] * D + colel, Us + wave * 2048 + c * 512);
    gl_lds16(Vbf + (size_t)dst[er] * D + colel, Vs + wave * 2048 + c * 512);
  }

  const int ctb = wave * 4;
  #define LOADB(Wp, kt, dst_)                                                 \
    _Pragma("unroll")                                                         \
    for (int nt = 0; nt < 4; ++nt)                                            \
      dst_[nt] = *(const bf16x8*)((Wp) + ((((kt) * 16 + ctb + nt) * 64 + lane) * 8));

  f32x4 acc[2][4];
  constexpr int DEPTH = 3;
  bf16x8 bqb[DEPTH][4];

  // ---------------- Layer 1: ea @ W1c (A from eaS) ----------------
  #pragma unroll
  for (int i = 0; i < 2; i++)
    #pragma unroll
    for (int j = 0; j < 4; j++)
      acc[i][j] = (f32x4){0.f, 0.f, 0.f, 0.f};
  #pragma unroll
  for (int d = 0; d < DEPTH; ++d) LOADB(W1c, d, bqb[d]);
  #pragma unroll
  for (int kt = 0; kt < 8; ++kt) {
    const int s = kt % DEPTH;
    bf16x8 afc[2];
    #pragma unroll
    for (int mt = 0; mt < 2; ++mt)
      afc[mt] = *(const bf16x8*)&eaS[(mt * 16 + lr) * 264 + (kt << 5) + lq * 8];
    #pragma unroll
    for (int mt = 0; mt < 2; ++mt)
      #pragma unroll
      for (int nt = 0; nt < 4; ++nt)
        acc[mt][nt] = __builtin_amdgcn_mfma_f32_16x16x32_bf16(afc[mt], bqb[s][nt], acc[mt][nt], 0, 0, 0);
    if (kt + DEPTH < 8) LOADB(W1c, kt + DEPTH, bqb[s]);
  }
  __syncthreads();   // drains UV gl_lds (vmcnt) + all eaS reads done

  // epilogue 1: acc += U + V + b1, relu (in regs)
  {
    float bv[4];
    #pragma unroll
    for (int nt = 0; nt < 4; ++nt) bv[nt] = b1[wave * 64 + nt * 16 + lr];
    #pragma unroll
    for (int mt = 0; mt < 2; ++mt)
      #pragma unroll
      for (int r = 0; r < 4; ++r) {
        const int row = mt * 16 + lq * 4 + r;
        #pragma unroll
        for (int nt = 0; nt < 4; ++nt) {
          const int col = wave * 64 + nt * 16 + lr;
          float v = acc[mt][nt][r] + bv[nt]
                  + bf2f(Us[row * 256 + col]) + bf2f(Vs[row * 256 + col]);
          acc[mt][nt][r] = v > 0.f ? v : 0.f;
        }
      }
  }
  __syncthreads();   // UV reads done; eaS->Hs overlay + ps overlay safe
  #pragma unroll
  for (int mt = 0; mt < 2; ++mt)
    #pragma unroll
    for (int r = 0; r < 4; ++r) {
      const int row = mt * 16 + lq * 4 + r;
      #pragma unroll
      for (int nt = 0; nt < 4; ++nt)
        Hs[row * 264 + wave * 64 + nt * 16 + lr] = f2bf(acc[mt][nt][r]);
    }
  __syncthreads();   // h1 visible

  // ---------------- Layer 2 (A from Hs) ----------------
  #pragma unroll
  for (int i = 0; i < 2; i++)
    #pragma unroll
    for (int j = 0; j < 4; j++)
      acc[i][j] = (f32x4){0.f, 0.f, 0.f, 0.f};
  #pragma unroll
  for (int d = 0; d < DEPTH; ++d) LOADB(W2, d, bqb[d]);
  #pragma unroll
  for (int kt = 0; kt < 8; ++kt) {
    const int s = kt % DEPTH;
    bf16x8 afc[2];
    #pragma unroll
    for (int mt = 0; mt < 2; ++mt)
      afc[mt] = *(const bf16x8*)&Hs[(mt * 16 + lr) * 264 + (kt << 5) + lq * 8];
    #pragma unroll
    for (int mt = 0; mt < 2; ++mt)
      #pragma unroll
      for (int nt = 0; nt < 4; ++nt)
        acc[mt][nt] = __builtin_amdgcn_mfma_f32_16x16x32_bf16(afc[mt], bqb[s][nt], acc[mt][nt], 0, 0, 0);
    if (kt + DEPTH < 8) LOADB(W2, kt + DEPTH, bqb[s]);
  }
  __syncthreads();   // h1 reads done before overwrite
  {
    float bv[4];
    #pragma unroll
    for (int nt = 0; nt < 4; ++nt) bv[nt] = b2[wave * 64 + nt * 16 + lr];
    #pragma unroll
    for (int mt = 0; mt < 2; ++mt)
      #pragma unroll
      for (int r = 0; r < 4; ++r) {
        const int row = mt * 16 + lq * 4 + r;
        #pragma unroll
        for (int nt = 0; nt < 4; ++nt) {
          float v = acc[mt][nt][r] + bv[nt];
          v = v > 0.f ? v : 0.f;
          Hs[row * 264 + wave * 64 + nt * 16 + lr] = f2bf(v);
        }
      }
  }
  __syncthreads();   // h2 visible

  // ---------------- Layer 3 + LN + staged residual ----------------
  #pragma unroll
  for (int i = 0; i < 2; i++)
    #pragma unroll
    for (int j = 0; j < 4; j++)
      acc[i][j] = (f32x4){0.f, 0.f, 0.f, 0.f};
  #pragma unroll
  for (int d = 0; d < DEPTH; ++d) LOADB(W3, d, bqb[d]);
  #pragma unroll
  for (int kt = 0; kt < 8; ++kt) {
    const int s = kt % DEPTH;
    bf16x8 afc[2];
    #pragma unroll
    for (int mt = 0; mt < 2; ++mt)
      afc[mt] = *(const bf16x8*)&Hs[(mt * 16 + lr) * 264 + (kt << 5) + lq * 8];
    #pragma unroll
    for (int mt = 0; mt < 2; ++mt)
      #pragma unroll
      for (int nt = 0; nt < 4; ++nt)
        acc[mt][nt] = __builtin_amdgcn_mfma_f32_16x16x32_bf16(afc[mt], bqb[s][nt], acc[mt][nt], 0, 0, 0);
    if (kt + DEPTH < 8) LOADB(W3, kt + DEPTH, bqb[s]);
  }
  #pragma unroll
  for (int nt = 0; nt < 4; ++nt) {
    const float bv = b3[wave * 64 + nt * 16 + lr];
    #pragma unroll
    for (int mt = 0; mt < 2; ++mt)
      #pragma unroll
      for (int r = 0; r < 4; ++r)
        acc[mt][nt][r] += bv;
  }
  #pragma unroll
  for (int mt = 0; mt < 2; ++mt) {
    #pragma unroll
    for (int r = 0; r < 4; ++r) {
      float s1 = 0.f, s2 = 0.f;
      #pragma unroll
      for (int nt = 0; nt < 4; ++nt) {
        float v = acc[mt][nt][r];
        s1 += v; s2 += v * v;
      }
      #pragma unroll
      for (int dlt = 1; dlt < 16; dlt <<= 1) {
        s1 += __shfl_xor(s1, dlt, 64);
        s2 += __shfl_xor(s2, dlt, 64);
      }
      if (lr == 0) {
        ps1[(mt * 16 + lq * 4 + r) * 4 + wave] = s1;
        ps2[(mt * 16 + lq * 4 + r) * 4 + wave] = s2;
      }
    }
  }
  __syncthreads();   // also: all Hs(h2) reads done -> delta overlay safe
  #pragma unroll
  for (int mt = 0; mt < 2; ++mt) {
    #pragma unroll
    for (int r = 0; r < 4; ++r) {
      const int rl = mt * 16 + lq * 4 + r;
      float fs1 = ps1[rl * 4 + 0] + ps1[rl * 4 + 1] + ps1[rl * 4 + 2] + ps1[rl * 4 + 3];
      float fs2 = ps2[rl * 4 + 0] + ps2[rl * 4 + 1] + ps2[rl * 4 + 2] + ps2[rl * 4 + 3];
      float mean = fs1 * (1.f / 256.f);
      float var  = fs2 * (1.f / 256.f) - mean * mean;
      float rstd = rsqrtf(var + 1e-5f);
      #pragma unroll
      for (int nt = 0; nt < 4; ++nt) {
        const int col = wave * 64 + nt * 16 + lr;
        float v = (acc[mt][nt][r] - mean) * rstd * lng[col] + lnb[col];
        Hs[rl * 264 + col] = f2bf(v);   // stage delta
      }
    }
  }
  __syncthreads();
  // coalesced RMW copyout: eabf += delta
  #pragma unroll
  for (int i = 0; i < 4; ++i) {
    int row = i * 8 + (tid >> 5);
    int cs  = (tid & 31) * 8;
    int er = r0 + row;
    if (er < E) {
      uint4 dv = *(const uint4*)&Hs[row * 264 + cs];
      uint4 ov = *(const uint4*)(eabf + (size_t)er * D + cs);
      const unsigned short* dp = (const unsigned short*)&dv;
      const unsigned short* op = (const unsigned short*)&ov;
      uint4 res;
      unsigned short* rp = (unsigned short*)&res;
      #pragma unroll
      for (int j = 0; j < 8; ++j) rp[j] = f2bf(bf2f(op[j]) + bf2f(dp[j]));
      *(uint4*)(eabf + (size_t)er * D + cs) = res;
    }
  }
  #undef LOADB
}

// Node MLP, 16-row tiles: x += LN(relu(relu([x,agg]@W1+b1)@W2+b2)@W3+b3)*g+bn
// fp32 resid RMW in xbuf + bf16 shadow xbf.
__global__ __launch_bounds__(256, 4) void fused_node(
    const unsigned short* __restrict__ xbf, const unsigned short* __restrict__ aggbf,
    const unsigned short* __restrict__ W1, const float* __restrict__ b1,
    const unsigned short* __restrict__ W2, const float* __restrict__ b2,
    const unsigned short* __restrict__ W3, const float* __restrict__ b3,
    const float* __restrict__ lng, const float* __restrict__ lnb,
    float* __restrict__ resid, unsigned short* __restrict__ bfout, int M)
{
  __shared__ __align__(16) unsigned short Hs[16 * 264];
  __shared__ float ps1[64];
  __shared__ float ps2[64];

  const int tid  = threadIdx.x;
  const int lane = tid & 63;
  const int wave = tid >> 6;
  const int lr   = lane & 15;
  const int lq   = lane >> 4;
  const int r0   = blockIdx.x * 16;

  int rw = r0 + lr; if (rw > M - 1) rw = M - 1;
  const int ro = rw * D;
  const int ctb = wave * 4;

  #define LOADB(Wp, kt, dst_)                                                 \
    _Pragma("unroll")                                                         \
    for (int nt = 0; nt < 4; ++nt)                                            \
      dst_[nt] = *(const bf16x8*)((Wp) + ((((kt) * 16 + ctb + nt) * 64 + lane) * 8));

  f32x4 acc[4];
  constexpr int DEPTH = 3;
  bf16x8 afb[DEPTH], bqb[DEPTH][4];

  // ---------------- Layer 1 (K=512: xbf then aggbf) ----------------
  #pragma unroll
  for (int j = 0; j < 4; j++) acc[j] = (f32x4){0.f, 0.f, 0.f, 0.f};
  #pragma unroll
  for (int d = 0; d < DEPTH; ++d) {
    afb[d] = *(const bf16x8*)(xbf + ro + (d << 5) + lq * 8);
    LOADB(W1, d, bqb[d]);
  }
  #pragma unroll
  for (int kt = 0; kt < 16; ++kt) {
    const int s = kt % DEPTH;
    #pragma unroll
    for (int nt = 0; nt < 4; ++nt)
      acc[nt] = __builtin_amdgcn_mfma_f32_16x16x32_bf16(afb[s], bqb[s][nt], acc[nt], 0, 0, 0);
    if (kt + DEPTH < 16) {
      const int kn = kt + DEPTH;
      const unsigned short* bp = (kn < 8) ? xbf : aggbf;
      afb[s] = *(const bf16x8*)(bp + ro + ((kn & 7) << 5) + lq * 8);
      LOADB(W1, kn, bqb[s]);
    }
  }
  {
    float bv[4];
    #pragma unroll
    for (int nt = 0; nt < 4; ++nt) bv[nt] = b1[wave * 64 + nt * 16 + lr];
    #pragma unroll
    for (int r = 0; r < 4; ++r) {
      const int row = lq * 4 + r;
      #pragma unroll
      for (int nt = 0; nt < 4; ++nt) {
        float v = acc[nt][r] + bv[nt];
        v = v > 0.f ? v : 0.f;
        Hs[row * 264 + wave * 64 + nt * 16 + lr] = f2bf(v);
      }
    }
  }
  __syncthreads();

  // ---------------- Layer 2 ----------------
  #pragma unroll
  for (int j = 0; j < 4; j++) acc[j] = (f32x4){0.f, 0.f, 0.f, 0.f};
  #pragma unroll
  for (int d = 0; d < DEPTH; ++d) LOADB(W2, d, bqb[d]);
  #pragma unroll
  for (int kt = 0; kt < 8; ++kt) {
    const int s = kt % DEPTH;
    bf16x8 afc = *(const bf16x8*)&Hs[lr * 264 + (kt << 5) + lq * 8];
    #pragma unroll
    for (int nt = 0; nt < 4; ++nt)
      acc[nt] = __builtin_amdgcn_mfma_f32_16x16x32_bf16(afc, bqb[s][nt], acc[nt], 0, 0, 0);
    if (kt + DEPTH < 8) LOADB(W2, kt + DEPTH, bqb[s]);
  }
  __syncthreads();
  {
    float bv[4];
    #pragma unroll
    for (int nt = 0; nt < 4; ++nt) bv[nt] = b2[wave * 64 + nt * 16 + lr];
    #pragma unroll
    for (int r = 0; r < 4; ++r) {
      const int row = lq * 4 + r;
      #pragma unroll
      for (int nt = 0; nt < 4; ++nt) {
        float v = acc[nt][r] + bv[nt];
        v = v > 0.f ? v : 0.f;
        Hs[row * 264 + wave * 64 + nt * 16 + lr] = f2bf(v);
      }
    }
  }
  __syncthreads();

  // ---------------- Layer 3 + LN + residual ----------------
  #pragma unroll
  for (int j = 0; j < 4; j++) acc[j] = (f32x4){0.f, 0.f, 0.f, 0.f};
  #pragma unroll
  for (int d = 0; d < DEPTH; ++d) LOADB(W3, d, bqb[d]);
  #pragma unroll
  for (int kt = 0; kt < 8; ++kt) {
    const int s = kt % DEPTH;
    bf16x8 afc = *(const bf16x8*)&Hs[lr * 264 + (kt << 5) + lq * 8];
    #pragma unroll
    for (int nt = 0; nt < 4; ++nt)
      acc[nt] = __builtin_amdgcn_mfma_f32_16x16x32_bf16(afc, bqb[s][nt], acc[nt], 0, 0, 0);
    if (kt + DEPTH < 8) LOADB(W3, kt + DEPTH, bqb[s]);
  }
  #pragma unroll
  for (int nt = 0; nt < 4; ++nt) {
    const float bv = b3[wave * 64 + nt * 16 + lr];
    #pragma unroll
    for (int r = 0; r < 4; ++r) acc[nt][r] += bv;
  }
  #pragma unroll
  for (int r = 0; r < 4; ++r) {
    float s1 = 0.f, s2 = 0.f;
    #pragma unroll
    for (int nt = 0; nt < 4; ++nt) {
      float v = acc[nt][r];
      s1 += v; s2 += v * v;
    }
    #pragma unroll
    for (int dlt = 1; dlt < 16; dlt <<= 1) {
      s1 += __shfl_xor(s1, dlt, 64);
      s2 += __shfl_xor(s2, dlt, 64);
    }
    if (lr == 0) {
      ps1[(lq * 4 + r) * 4 + wave] = s1;
      ps2[(lq * 4 + r) * 4 + wave] = s2;
    }
  }
  __syncthreads();
  #pragma unroll
  for (int r = 0; r < 4; ++r) {
    const int rl = lq * 4 + r;
    const int row = r0 + rl;
    float fs1 = ps1[rl * 4 + 0] + ps1[rl * 4 + 1] + ps1[rl * 4 + 2] + ps1[rl * 4 + 3];
    float fs2 = ps2[rl * 4 + 0] + ps2[rl * 4 + 1] + ps2[rl * 4 + 2] + ps2[rl * 4 + 3];
    float mean = fs1 * (1.f / 256.f);
    float var  = fs2 * (1.f / 256.f) - mean * mean;
    float rstd = rsqrtf(var + 1e-5f);
    if (row < M) {
      #pragma unroll
      for (int nt = 0; nt < 4; ++nt) {
        const int col = wave * 64 + nt * 16 + lr;
        float v = (acc[nt][r] - mean) * rstd * lng[col] + lnb[col];
        float* rp = resid + (size_t)row * D + col;
        float nv = *rp + v;
        *rp = nv;
        bfout[(size_t)row * D + col] = f2bf(nv);
      }
    }
  }
  #undef LOADB
}

extern "C" void kernel_launch(void* const* d_in, const int* in_sizes, int n_in,
                              void* d_out, int out_size, void* d_ws, size_t ws_size,
                              hipStream_t stream) {
  const float* x         = (const float*)d_in[0];
  const int*   eidx      = (const int*)d_in[1];
  const float* edge_attr = (const float*)d_in[2];
  const float* eW1 = (const float*)d_in[3];
  const float* eB1 = (const float*)d_in[4];
  const float* eW2 = (const float*)d_in[5];
  const float* eB2 = (const float*)d_in[6];
  const float* eW3 = (const float*)d_in[7];
  const float* eB3 = (const float*)d_in[8];
  const float* eLNg = (const float*)d_in[9];
  const float* eLNb = (const float*)d_in[10];
  const float* nW1 = (const float*)d_in[11];
  const float* nB1 = (const float*)d_in[12];
  const float* nW2 = (const float*)d_in[13];
  const float* nB2 = (const float*)d_in[14];
  const float* nW3 = (const float*)d_in[15];
  const float* nB3 = (const float*)d_in[16];
  const float* nLNg = (const float*)d_in[17];
  const float* nLNb = (const float*)d_in[18];

  const int Nn = in_sizes[0] / D;   // 10000
  const int E  = in_sizes[1] / 2;   // 60000
  const int B  = in_sizes[4] / D;   // 9

  const int* srcI = eidx;
  const int* dstI = eidx + E;

  char* wsp = (char*)d_ws;
  size_t off = 0;
  auto alloc = [&](size_t bytes) {
    char* p = wsp + off;
    off += (bytes + 255) & ~(size_t)255;
    return p;
  };
  unsigned short* eW1at = (unsigned short*)alloc((size_t)B * 256 * D * 2);
  unsigned short* eW1bt = (unsigned short*)alloc((size_t)B * 256 * D * 2);
  unsigned short* eW1ct = (unsigned short*)alloc((size_t)B * 256 * D * 2);
  unsigned short* eW2t  = (unsigned short*)alloc((size_t)B * 256 * D * 2);
  unsigned short* eW3t  = (unsigned short*)alloc((size_t)B * 256 * D * 2);
  unsigned short* nW1t  = (unsigned short*)alloc((size_t)B * 512 * D * 2);
  unsigned short* nW2t  = (unsigned short*)alloc((size_t)B * 256 * D * 2);
  unsigned short* nW3t  = (unsigned short*)alloc((size_t)B * 256 * D * 2);
  unsigned short* eabf  = (unsigned short*)alloc((size_t)E * D * 2);
  unsigned short* xbf   = (unsigned short*)alloc((size_t)Nn * D * 2);
  unsigned short* aggbf = (unsigned short*)alloc((size_t)Nn * D * 2);
  unsigned short* Ubf   = (unsigned short*)alloc((size_t)Nn * D * 2);
  unsigned short* Vbf   = (unsigned short*)alloc((size_t)Nn * D * 2);
  int*            hist  = (int*)alloc((size_t)(Nn + 1) * 4);
  int*            offs  = (int*)alloc((size_t)(Nn + 1) * 4);
  int*            cnt   = (int*)alloc((size_t)Nn * 4);
  int*            eid   = (int*)alloc((size_t)E * 4);

  float* xbuf = (float*)d_out;  // x state lives in d_out

  auto wp = [&](const float* w, unsigned short* wt, int Kfull, int k0, int Ksub) {
    int total = B * Ksub * D;
    wprep_kernel<<<(total + 255) / 256, 256, 0, stream>>>(w, wt, Kfull, k0, Ksub, total);
  };
  wp(eW1, eW1at, 768, 0, 256);
  wp(eW1, eW1bt, 768, 256, 256);
  wp(eW1, eW1ct, 768, 512, 256);
  wp(eW2, eW2t, 256, 0, 256);
  wp(eW3, eW3t, 256, 0, 256);
  wp(nW1, nW1t, 512, 0, 512);
  wp(nW2, nW2t, 256, 0, 256);
  wp(nW3, nW3t, 256, 0, 256);

  hipMemcpyAsync(xbuf, x, (size_t)Nn * D * 4, hipMemcpyDeviceToDevice, stream);
  {
    int n4 = E * D / 4;
    cvt_bf16_kernel<<<(n4 + 255) / 256, 256, 0, stream>>>(
        (const float4*)edge_attr, (ushort4*)eabf, n4);
    int m4 = Nn * D / 4;
    cvt_bf16_kernel<<<(m4 + 255) / 256, 256, 0, stream>>>(
        (const float4*)x, (ushort4*)xbf, m4);
  }

  // CSR build (edge_index constant across blocks -> once per launch)
  hipMemsetAsync(hist, 0, (size_t)Nn * 4, stream);
  hipMemsetAsync(cnt, 0, (size_t)Nn * 4, stream);
  hist_kernel<<<(E + 255) / 256, 256, 0, stream>>>(dstI, hist, E);
  scan_kernel<<<1, 256, 0, stream>>>(hist, offs, Nn);
  fill_kernel<<<(E + 255) / 256, 256, 0, stream>>>(dstI, offs, cnt, eid, E);

  const int gridE  = (E + 31) / 32;        // 1875
  const int gridN  = (Nn + 15) / 16;       // 625
  const int gridUV = gridN * 2;            // 1250
  const int gridA  = (Nn + 3) / 4;         // 2500

  for (int b = 0; b < B; ++b) {
    // U = x@W1a, V = x@W1b (one launch, interleaved blocks)
    gemm_uv<<<gridUV, 256, 0, stream>>>(
        xbf, eW1at + (size_t)b * 256 * D, eW1bt + (size_t)b * 256 * D, Ubf, Vbf, Nn);
    // edge: ea += LN(MLP(U[src]+V[dst]+ea@W1c))
    fused_edge<<<gridE, 256, 0, stream>>>(
        eabf, srcI, dstI, Ubf, Vbf,
        eW1ct + (size_t)b * 256 * D, eB1 + b * D,
        eW2t + (size_t)b * 256 * D, eB2 + b * D,
        eW3t + (size_t)b * 256 * D, eB3 + b * D,
        eLNg + b * D, eLNb + b * D, E);
    // agg = segment_sum(ea, dst) via CSR gather
    agg_kernel<<<gridA, 256, 0, stream>>>(eabf, eid, offs, aggbf, Nn);
    // node: x += LN(MLP([x, agg]))
    fused_node<<<gridN, 256, 0, stream>>>(
        xbf, aggbf,
        nW1t + (size_t)b * 512 * D, nB1 + b * D,
        nW2t + (size_t)b * 256 * D, nB2 + b * D,
        nW3t + (size_t)b * 256 * D, nB3 + b * D,
        nLNg + b * D, nLNb + b * D, xbuf, xbf, Nn);
  }
}